// Round 1
// baseline (13192.366 us; speedup 1.0000x reference)
//
#include <hip/hip_runtime.h>
#include <stdint.h>

// ---------------- common ----------------
using bf16x8 = __attribute__((ext_vector_type(8))) short;
using f32x4  = __attribute__((ext_vector_type(4))) float;

#define MFMA(a,b,c) __builtin_amdgcn_mfma_f32_16x16x32_bf16((a),(b),(c),0,0,0)

static __device__ __forceinline__ unsigned short f2bf(float x){
  union { float f; uint32_t u; } v; v.f = x;
  return (unsigned short)((v.u + 0x7fffu + ((v.u >> 16) & 1u)) >> 16);
}
static __device__ __forceinline__ float sigm(float x){ return 1.0f/(1.0f+__expf(-x)); }
static __device__ __forceinline__ float tanh_(float x){ return 1.0f - 2.0f/(1.0f+__expf(2.0f*x)); }
// LDS addressing: 512-col bf16 rows (1024B stride) + XOR swizzle (T2) so
// stride-1KB column reads don't 16-way bank-conflict.
static __device__ __forceinline__ int lofs(int row, int col){
  return ((row<<10) + (col<<1)) ^ ((row&7)<<4);
}

// ---------------- workspace layout (bytes) ----------------
constexpr size_t OFF_WHHN  = 0;                              // (2048,512) bf16
constexpr size_t OFF_WHHE  = OFF_WHHN  + 2048*512*2;
constexpr size_t OFF_WIHN  = OFF_WHHE  + 2048*512*2;         // (2048,256) bf16
constexpr size_t OFF_WIHE1 = OFF_WIHN  + 2048*256*2;         // Wih_e[:, :256]
constexpr size_t OFF_WIHE2 = OFF_WIHE1 + 2048*256*2;         // Wih_e[:, 256:]
constexpr size_t OFF_WN1   = OFF_WIHE2 + 2048*256*2;         // (256,512)
constexpr size_t OFF_WN2   = OFF_WN1   + 256*512*2;          // (256,256)
constexpr size_t OFF_WE1   = OFF_WN2   + 256*256*2;          // (512,512)
constexpr size_t OFF_WE2   = OFF_WE1   + 512*512*2;          // (256,512)
constexpr size_t OFF_WE3   = OFF_WE2   + 256*512*2;          // (256,256)
constexpr size_t OFF_WSF   = OFF_WE3   + 256*256*2;          // [Ws1;Wf1] (256,256)
constexpr size_t OFF_WS2   = OFF_WSF   + 256*256*2;          // (2,128)
constexpr size_t OFF_WF2   = OFF_WS2   + 2*128*2 + 512;      // (128,128), padded
constexpr size_t OFF_GENE  = OFF_WF2   + 128*128*2;          // (256,256) bf16
constexpr size_t OFF_H0    = OFF_GENE  + 256*256*2;          // node h dbuf0 bf16
constexpr size_t OFF_H1    = OFF_H0    + 256*512*2;
constexpr size_t OFF_TN    = OFF_H1    + 256*512*2;          // (256,256) bf16
constexpr size_t OFF_ENTRY = OFF_TN    + 256*256*2;          // (256,256) bf16
constexpr size_t OFF_C     = OFF_ENTRY + 256*256*2;          // node c f32
constexpr size_t OFF_XWN   = OFF_C     + 256*512*4;          // (256,2048) f32
constexpr size_t OFF_XWEG  = OFF_XWN   + 256*2048*4;         // (256,2048) f32
constexpr size_t OFF_BN    = OFF_XWEG  + 256*2048*4;         // 2048 f32
constexpr size_t OFF_BE    = OFF_BN    + 2048*4;
constexpr size_t OFF_BSF   = OFF_BE    + 2048*4;             // 256 f32
constexpr size_t OFF_XWEALL= OFF_BSF   + 256*4 + 1024 - ((256*4)%1024); // align
constexpr size_t WS_NEED   = OFF_XWEALL + (size_t)62*256*2048*4;

// ---------------- prep: fp32 -> bf16 packs, fused biases ----------------
struct PrepArgs {
  const float *Whh_n, *Whh_e, *Wih_n, *Wih_e, *Wn1, *Wn2, *We1, *We2, *We3,
              *Ws1, *Ws2, *Wf1, *Wf2, *gene, *h0n, *c0n,
              *bihn, *bhhn, *bihe, *bhhe, *bs1, *bf1;
  unsigned short *oWhhN, *oWhhE, *oWihN, *oWihE1, *oWihE2, *oWn1, *oWn2,
                 *oWe1, *oWe2, *oWe3, *oWsf, *oWs2, *oWf2, *oGene, *oH0;
  float *oC, *oBn, *oBe, *oBsf;
};

__global__ void k_prep(PrepArgs a){
  const size_t stride = (size_t)gridDim.x * blockDim.x;
  for (size_t i = (size_t)blockIdx.x*blockDim.x + threadIdx.x; i < 4739584u; i += stride) {
    size_t t = i;
    if (t < 1048576) { a.oWhhN[t] = f2bf(a.Whh_n[t]); continue; } t -= 1048576;
    if (t < 1048576) { a.oWhhE[t] = f2bf(a.Whh_e[t]); continue; } t -= 1048576;
    if (t < 524288)  { a.oWihN[t] = f2bf(a.Wih_n[t]); continue; } t -= 524288;
    if (t < 524288)  { a.oWihE1[t] = f2bf(a.Wih_e[(t>>8)*512 + (t&255)]); continue; } t -= 524288;
    if (t < 524288)  { a.oWihE2[t] = f2bf(a.Wih_e[(t>>8)*512 + 256 + (t&255)]); continue; } t -= 524288;
    if (t < 131072)  { a.oWn1[t] = f2bf(a.Wn1[t]); continue; } t -= 131072;
    if (t < 65536)   { a.oWn2[t] = f2bf(a.Wn2[t]); continue; } t -= 65536;
    if (t < 262144)  { a.oWe1[t] = f2bf(a.We1[t]); continue; } t -= 262144;
    if (t < 131072)  { a.oWe2[t] = f2bf(a.We2[t]); continue; } t -= 131072;
    if (t < 65536)   { a.oWe3[t] = f2bf(a.We3[t]); continue; } t -= 65536;
    if (t < 65536)   { a.oWsf[t] = f2bf(t < 32768 ? a.Ws1[t] : a.Wf1[t-32768]); continue; } t -= 65536;
    if (t < 256)     { a.oWs2[t] = f2bf(a.Ws2[t]); continue; } t -= 256;
    if (t < 16384)   { a.oWf2[t] = f2bf(a.Wf2[t]); continue; } t -= 16384;
    if (t < 65536)   { a.oGene[t] = f2bf(a.gene[t]); continue; } t -= 65536;
    if (t < 131072)  { a.oH0[t] = f2bf(a.h0n[t]); continue; } t -= 131072;
    if (t < 131072)  { a.oC[t] = a.c0n[t]; continue; } t -= 131072;
    if (t < 2048)    { a.oBn[t] = a.bihn[t] + a.bhhn[t]; continue; } t -= 2048;
    if (t < 2048)    { a.oBe[t] = a.bihe[t] + a.bhhe[t]; continue; } t -= 2048;
    if (t < 256)     { a.oBsf[t] = (t < 128) ? a.bs1[t] : a.bf1[t-128]; }
  }
}

// ---------------- generic MLP: out = act(A(256,K) @ W(N,K)^T + bias + pre) ----------------
__global__ __launch_bounds__(256) void k_mlp(
    const unsigned short* __restrict__ A, const unsigned short* __restrict__ W,
    const float* __restrict__ bias, const float* __restrict__ pre,
    float* __restrict__ outf, unsigned short* __restrict__ outb,
    int K, int N, int relu)
{
  const int tid = threadIdx.x, lane = tid & 63, w = tid >> 6;
  const int l15 = lane & 15, l4 = lane >> 4;
  const int m0 = blockIdx.x * 64;
  const int n0 = blockIdx.y * 64 + w * 16;
  const f32x4 fz = {0.f,0.f,0.f,0.f};
  f32x4 acc[4];
  #pragma unroll
  for (int mf=0;mf<4;++mf) acc[mf] = fz;
  const int nk = K >> 5;
  for (int kk=0;kk<nk;++kk) {
    const int k = kk*32 + l4*8;
    bf16x8 b = *(const bf16x8*)(W + (size_t)(n0 + l15)*K + k);
    #pragma unroll
    for (int mf=0;mf<4;++mf) {
      bf16x8 a = *(const bf16x8*)(A + (size_t)(m0 + mf*16 + l15)*K + k);
      acc[mf] = MFMA(a, b, acc[mf]);
    }
  }
  const int col = n0 + l15;
  const float bb = bias ? bias[col] : 0.f;
  #pragma unroll
  for (int mf=0;mf<4;++mf)
  #pragma unroll
  for (int r=0;r<4;++r) {
    const int row = m0 + mf*16 + l4*4 + r;
    float v = acc[mf][r] + bb;
    if (pre) v += pre[(size_t)row*N + col];
    if (relu && v < 0.f) v = 0.f;
    const size_t o = (size_t)row*N + col;
    if (outf) outf[o] = v;
    if (outb) outb[o] = f2bf(v);
  }
}

// ---------------- node LSTM step: gates = xwn + h@Whh^T, pointwise ----------------
__global__ __launch_bounds__(256) void k_lstm_node(
    const unsigned short* __restrict__ hin, float* __restrict__ c,
    const float* __restrict__ xwn, const unsigned short* __restrict__ Whh,
    unsigned short* __restrict__ hout)
{
  const int tid = threadIdx.x, lane = tid & 63, w = tid >> 6;
  const int l15 = lane & 15, l4 = lane >> 4;
  const int m0 = blockIdx.x * 64;
  const int colb = blockIdx.y * 64 + w * 16;
  f32x4 acc[4][4]; // [mf][gate]
  #pragma unroll
  for (int mf=0;mf<4;++mf)
  #pragma unroll
  for (int g=0;g<4;++g) {
    f32x4 a;
    #pragma unroll
    for (int r=0;r<4;++r)
      a[r] = xwn[(size_t)(m0 + mf*16 + l4*4 + r)*2048 + g*512 + colb + l15];
    acc[mf][g] = a;
  }
  for (int kk=0;kk<16;++kk) {
    const int k = kk*32 + l4*8;
    bf16x8 a[4];
    #pragma unroll
    for (int mf=0;mf<4;++mf)
      a[mf] = *(const bf16x8*)(hin + (size_t)(m0 + mf*16 + l15)*512 + k);
    #pragma unroll
    for (int g=0;g<4;++g) {
      bf16x8 b = *(const bf16x8*)(Whh + (size_t)(g*512 + colb + l15)*512 + k);
      #pragma unroll
      for (int mf=0;mf<4;++mf) acc[mf][g] = MFMA(a[mf], b, acc[mf][g]);
    }
  }
  const int col = colb + l15;
  #pragma unroll
  for (int mf=0;mf<4;++mf)
  #pragma unroll
  for (int r=0;r<4;++r) {
    const size_t idx = (size_t)(m0 + mf*16 + l4*4 + r)*512 + col;
    float cn = sigm(acc[mf][1][r]) * c[idx] + sigm(acc[mf][0][r]) * tanh_(acc[mf][2][r]);
    c[idx] = cn;
    hout[idx] = f2bf(sigm(acc[mf][3][r]) * tanh_(cn));
  }
}

// ---------------- persistent edge kernel ----------------
// grid = 248 WGs of 512 thr: (pair p in [0,31)) x (gtile in [0,8)); each WG runs
// chain s=p then s=61-p (63 steps total -> load balanced), 32 batch rows.
__global__ __launch_bounds__(512, 2) void k_edge(
    const float* __restrict__ h0e, const float* __restrict__ c0e,
    const float* __restrict__ xweall,
    const unsigned short* __restrict__ Whh,
    const unsigned short* __restrict__ We1, const float* __restrict__ be1,
    const unsigned short* __restrict__ We2, const float* __restrict__ be2,
    const unsigned short* __restrict__ We3, const float* __restrict__ be3,
    const unsigned short* __restrict__ Wsf, const float* __restrict__ bsf,
    const unsigned short* __restrict__ Ws2, const float* __restrict__ bs2,
    const unsigned short* __restrict__ Wf2, const float* __restrict__ bf2,
    float* __restrict__ out)
{
  __shared__ char smem[98304];
  char* heL = smem;           // 32x512 bf16, swizzled
  char* tA  = smem + 32768;   // t1 / t
  char* tB  = smem + 65536;   // t2 / u

  const int tid = threadIdx.x;
  const int lane = tid & 63;
  const int w = tid >> 6;       // wave 0..7, owns he-cols [w*64, w*64+64)
  const int l15 = lane & 15;
  const int l4 = lane >> 4;
  const int pair = blockIdx.x >> 3;
  const int g0 = (blockIdx.x & 7) * 32;
  const f32x4 fz = {0.f,0.f,0.f,0.f};
  const size_t FE = 1048576;

  for (int half = 0; half < 2; ++half) {
    const int s = half ? 61 - pair : pair;
    __syncthreads();
    // he0 -> LDS (bf16, swizzled)
    for (int idx = tid; idx < 32*512; idx += 512) {
      int r = idx >> 9, cc = idx & 511;
      *(unsigned short*)(heL + lofs(r, cc)) = f2bf(h0e[((size_t)s*256 + g0 + r)*512 + cc]);
    }
    // ce0 -> regs, aligned with D-frag layout
    float ce[2][4][4];
    #pragma unroll
    for (int mf=0;mf<2;++mf)
    #pragma unroll
    for (int cf=0;cf<4;++cf)
    #pragma unroll
    for (int r=0;r<4;++r)
      ce[mf][cf][r] = c0e[((size_t)s*256 + g0 + mf*16 + l4*4 + r)*512 + w*64 + cf*16 + l15];
    __syncthreads();

    const float* xwe = xweall + (size_t)s*256*2048;

    for (int j = 0; j <= s; ++j) {
      // ---- LSTM gates: acc = xwe + he @ Whh^T ----
      f32x4 acc[2][4][4]; // [mf][gate][colfrag]
      #pragma unroll
      for (int mf=0;mf<2;++mf)
      #pragma unroll
      for (int g=0;g<4;++g)
      #pragma unroll
      for (int cf=0;cf<4;++cf) {
        f32x4 a;
        #pragma unroll
        for (int r=0;r<4;++r)
          a[r] = xwe[(size_t)(g0 + mf*16 + l4*4 + r)*2048 + g*512 + w*64 + cf*16 + l15];
        acc[mf][g][cf] = a;
      }
      for (int kk=0;kk<16;++kk) {
        const int k = kk*32 + l4*8;
        bf16x8 a0 = *(const bf16x8*)(heL + lofs(l15, k));
        bf16x8 a1 = *(const bf16x8*)(heL + lofs(16 + l15, k));
        #pragma unroll
        for (int g=0;g<4;++g)
        #pragma unroll
        for (int cf=0;cf<4;++cf) {
          bf16x8 b = *(const bf16x8*)(Whh + (size_t)(g*512 + w*64 + cf*16 + l15)*512 + k);
          acc[0][g][cf] = MFMA(a0, b, acc[0][g][cf]);
          acc[1][g][cf] = MFMA(a1, b, acc[1][g][cf]);
        }
      }
      __syncthreads(); // S1: he fully read
      // ---- pointwise, write he_new ----
      #pragma unroll
      for (int mf=0;mf<2;++mf)
      #pragma unroll
      for (int cf=0;cf<4;++cf) {
        const int col = w*64 + cf*16 + l15;
        #pragma unroll
        for (int r=0;r<4;++r) {
          float cn = sigm(acc[mf][1][cf][r]) * ce[mf][cf][r]
                   + sigm(acc[mf][0][cf][r]) * tanh_(acc[mf][2][cf][r]);
          ce[mf][cf][r] = cn;
          *(unsigned short*)(heL + lofs(mf*16 + l4*4 + r, col)) = f2bf(sigm(acc[mf][3][cf][r]) * tanh_(cn));
        }
      }
      __syncthreads(); // S2: he_new ready
      // ---- FF1: t1 = relu(he @ We1^T + be1) -> tA (512 cols) ----
      {
        f32x4 fa[2][4];
        #pragma unroll
        for (int mf=0;mf<2;++mf)
        #pragma unroll
        for (int nf=0;nf<4;++nf) fa[mf][nf] = fz;
        for (int kk=0;kk<16;++kk) {
          const int k = kk*32 + l4*8;
          bf16x8 a0 = *(const bf16x8*)(heL + lofs(l15, k));
          bf16x8 a1 = *(const bf16x8*)(heL + lofs(16 + l15, k));
          #pragma unroll
          for (int nf=0;nf<4;++nf) {
            bf16x8 b = *(const bf16x8*)(We1 + (size_t)(w*64 + nf*16 + l15)*512 + k);
            fa[0][nf] = MFMA(a0, b, fa[0][nf]);
            fa[1][nf] = MFMA(a1, b, fa[1][nf]);
          }
        }
        #pragma unroll
        for (int mf=0;mf<2;++mf)
        #pragma unroll
        for (int nf=0;nf<4;++nf) {
          const int col = w*64 + nf*16 + l15;
          const float bb = be1[col];
          #pragma unroll
          for (int r=0;r<4;++r) {
            float v = fa[mf][nf][r] + bb;
            *(unsigned short*)(tA + lofs(mf*16 + l4*4 + r, col)) = f2bf(v > 0.f ? v : 0.f);
          }
        }
      }
      __syncthreads(); // S3
      // ---- FF2: t2 = relu(t1 @ We2^T + be2) -> tB (256 cols) ----
      {
        f32x4 fa[2][2] = {{fz,fz},{fz,fz}};
        for (int kk=0;kk<16;++kk) {
          const int k = kk*32 + l4*8;
          bf16x8 a0 = *(const bf16x8*)(tA + lofs(l15, k));
          bf16x8 a1 = *(const bf16x8*)(tA + lofs(16 + l15, k));
          #pragma unroll
          for (int nf=0;nf<2;++nf) {
            bf16x8 b = *(const bf16x8*)(We2 + (size_t)(w*32 + nf*16 + l15)*512 + k);
            fa[0][nf] = MFMA(a0, b, fa[0][nf]);
            fa[1][nf] = MFMA(a1, b, fa[1][nf]);
          }
        }
        #pragma unroll
        for (int mf=0;mf<2;++mf)
        #pragma unroll
        for (int nf=0;nf<2;++nf) {
          const int col = w*32 + nf*16 + l15;
          const float bb = be2[col];
          #pragma unroll
          for (int r=0;r<4;++r) {
            float v = fa[mf][nf][r] + bb;
            *(unsigned short*)(tB + lofs(mf*16 + l4*4 + r, col)) = f2bf(v > 0.f ? v : 0.f);
          }
        }
      }
      __syncthreads(); // S4
      // ---- FF3: t = t2 @ We3^T + be3 (no relu) -> tA cols 0..255 ----
      {
        f32x4 fa[2][2] = {{fz,fz},{fz,fz}};
        for (int kk=0;kk<8;++kk) {
          const int k = kk*32 + l4*8;
          bf16x8 a0 = *(const bf16x8*)(tB + lofs(l15, k));
          bf16x8 a1 = *(const bf16x8*)(tB + lofs(16 + l15, k));
          #pragma unroll
          for (int nf=0;nf<2;++nf) {
            bf16x8 b = *(const bf16x8*)(We3 + (size_t)(w*32 + nf*16 + l15)*256 + k);
            fa[0][nf] = MFMA(a0, b, fa[0][nf]);
            fa[1][nf] = MFMA(a1, b, fa[1][nf]);
          }
        }
        #pragma unroll
        for (int mf=0;mf<2;++mf)
        #pragma unroll
        for (int nf=0;nf<2;++nf) {
          const int col = w*32 + nf*16 + l15;
          const float bb = be3[col];
          #pragma unroll
          for (int r=0;r<4;++r)
            *(unsigned short*)(tA + lofs(mf*16 + l4*4 + r, col)) = f2bf(fa[mf][nf][r] + bb);
        }
      }
      __syncthreads(); // S5
      // ---- u = relu(t @ [Ws1;Wf1]^T + [bs1;bf1]) -> tB cols 0..255 ----
      {
        f32x4 fa[2][2] = {{fz,fz},{fz,fz}};
        for (int kk=0;kk<8;++kk) {
          const int k = kk*32 + l4*8;
          bf16x8 a0 = *(const bf16x8*)(tA + lofs(l15, k));
          bf16x8 a1 = *(const bf16x8*)(tA + lofs(16 + l15, k));
          #pragma unroll
          for (int nf=0;nf<2;++nf) {
            bf16x8 b = *(const bf16x8*)(Wsf + (size_t)(w*32 + nf*16 + l15)*256 + k);
            fa[0][nf] = MFMA(a0, b, fa[0][nf]);
            fa[1][nf] = MFMA(a1, b, fa[1][nf]);
          }
        }
        #pragma unroll
        for (int mf=0;mf<2;++mf)
        #pragma unroll
        for (int nf=0;nf<2;++nf) {
          const int col = w*32 + nf*16 + l15;
          const float bb = bsf[col];
          #pragma unroll
          for (int r=0;r<4;++r) {
            float v = fa[mf][nf][r] + bb;
            *(unsigned short*)(tB + lofs(mf*16 + l4*4 + r, col)) = f2bf(v > 0.f ? v : 0.f);
          }
        }
      }
      __syncthreads(); // S6
      // ---- ft = u[:,128:] @ Wf2^T + bf2 -> fe scatter ----
      {
        f32x4 fa[2] = {fz, fz};
        for (int kk=0;kk<4;++kk) {
          const int k = kk*32 + l4*8;
          bf16x8 a0 = *(const bf16x8*)(tB + lofs(l15, 128 + k));
          bf16x8 a1 = *(const bf16x8*)(tB + lofs(16 + l15, 128 + k));
          bf16x8 b = *(const bf16x8*)(Wf2 + (size_t)(w*16 + l15)*128 + k);
          fa[0] = MFMA(a0, b, fa[0]);
          fa[1] = MFMA(a1, b, fa[1]);
        }
        const int colf = w*16 + l15;
        const float bb = bf2[colf];
        #pragma unroll
        for (int mf=0;mf<2;++mf)
        #pragma unroll
        for (int r=0;r<4;++r) {
          const int g = g0 + mf*16 + l4*4 + r;
          size_t o = (colf < 64)
            ? FE + (size_t)g*262144 + (size_t)(s+2)*4096 + (size_t)j*64 + colf
            : FE + (size_t)g*262144 + (size_t)j*4096 + (size_t)(s+2)*64 + (colf-64);
          out[o] = fa[mf][r] + bb;
        }
      }
      // ---- sc = sigmoid(u[:,:128] @ Ws2^T + bs2) -> ex scatter (wave 0) ----
      if (w == 0) {
        f32x4 fa[2] = {fz, fz};
        const bf16x8 bz = {0,0,0,0,0,0,0,0};
        for (int kk=0;kk<4;++kk) {
          const int k = kk*32 + l4*8;
          bf16x8 a0 = *(const bf16x8*)(tB + lofs(l15, k));
          bf16x8 a1 = *(const bf16x8*)(tB + lofs(16 + l15, k));
          bf16x8 b = (l15 < 2) ? *(const bf16x8*)(Ws2 + (size_t)l15*128 + k) : bz;
          fa[0] = MFMA(a0, b, fa[0]);
          fa[1] = MFMA(a1, b, fa[1]);
        }
        if (l15 < 2) {
          const float bb = bs2[l15];
          #pragma unroll
          for (int mf=0;mf<2;++mf)
          #pragma unroll
          for (int r=0;r<4;++r) {
            const int g = g0 + mf*16 + l4*4 + r;
            float v = sigm(fa[mf][r] + bb);
            size_t o = (l15 == 0)
              ? (size_t)g*4096 + (size_t)(s+2)*64 + j
              : (size_t)g*4096 + (size_t)j*64 + (s+2);
            out[o] = v;
          }
        }
      }
    } // j
  } // half
}

// ---------------- launch ----------------
extern "C" void kernel_launch(void* const* d_in, const int* in_sizes, int n_in,
                              void* d_out, int out_size, void* d_ws, size_t ws_size,
                              hipStream_t stream)
{
  (void)in_sizes; (void)n_in;
  if (ws_size < WS_NEED) return; // workspace too small: fail visibly

  const float* gene  = (const float*)d_in[0];
  const float* Wih_n = (const float*)d_in[1];
  const float* Whh_n = (const float*)d_in[2];
  const float* bih_n = (const float*)d_in[3];
  const float* bhh_n = (const float*)d_in[4];
  const float* Wih_e = (const float*)d_in[5];
  const float* Whh_e = (const float*)d_in[6];
  const float* bih_e = (const float*)d_in[7];
  const float* bhh_e = (const float*)d_in[8];
  const float* Wn1   = (const float*)d_in[9];
  const float* bn1   = (const float*)d_in[10];
  const float* Wn2   = (const float*)d_in[11];
  const float* bn2   = (const float*)d_in[12];
  const float* We1   = (const float*)d_in[13];
  const float* be1   = (const float*)d_in[14];
  const float* We2   = (const float*)d_in[15];
  const float* be2   = (const float*)d_in[16];
  const float* We3   = (const float*)d_in[17];
  const float* be3   = (const float*)d_in[18];
  const float* Ws1   = (const float*)d_in[19];
  const float* bs1   = (const float*)d_in[20];
  const float* Ws2   = (const float*)d_in[21];
  const float* bs2   = (const float*)d_in[22];
  const float* Wf1   = (const float*)d_in[23];
  const float* bf1   = (const float*)d_in[24];
  const float* Wf2   = (const float*)d_in[25];
  const float* bf2   = (const float*)d_in[26];
  const float* h0n   = (const float*)d_in[27];
  const float* c0n   = (const float*)d_in[28];
  const float* h0e   = (const float*)d_in[29];
  const float* c0e   = (const float*)d_in[30];

  char* ws = (char*)d_ws;
  auto U16 = [&](size_t o){ return (unsigned short*)(ws + o); };
  auto F32 = [&](size_t o){ return (float*)(ws + o); };

  hipMemsetAsync(d_out, 0, (size_t)out_size * sizeof(float), stream);

  PrepArgs pa;
  pa.Whh_n=Whh_n; pa.Whh_e=Whh_e; pa.Wih_n=Wih_n; pa.Wih_e=Wih_e;
  pa.Wn1=Wn1; pa.Wn2=Wn2; pa.We1=We1; pa.We2=We2; pa.We3=We3;
  pa.Ws1=Ws1; pa.Ws2=Ws2; pa.Wf1=Wf1; pa.Wf2=Wf2; pa.gene=gene;
  pa.h0n=h0n; pa.c0n=c0n; pa.bihn=bih_n; pa.bhhn=bhh_n; pa.bihe=bih_e;
  pa.bhhe=bhh_e; pa.bs1=bs1; pa.bf1=bf1;
  pa.oWhhN=U16(OFF_WHHN); pa.oWhhE=U16(OFF_WHHE); pa.oWihN=U16(OFF_WIHN);
  pa.oWihE1=U16(OFF_WIHE1); pa.oWihE2=U16(OFF_WIHE2); pa.oWn1=U16(OFF_WN1);
  pa.oWn2=U16(OFF_WN2); pa.oWe1=U16(OFF_WE1); pa.oWe2=U16(OFF_WE2);
  pa.oWe3=U16(OFF_WE3); pa.oWsf=U16(OFF_WSF); pa.oWs2=U16(OFF_WS2);
  pa.oWf2=U16(OFF_WF2); pa.oGene=U16(OFF_GENE); pa.oH0=U16(OFF_H0);
  pa.oC=F32(OFF_C); pa.oBn=F32(OFF_BN); pa.oBe=F32(OFF_BE); pa.oBsf=F32(OFF_BSF);
  k_prep<<<1024, 256, 0, stream>>>(pa);

  // constant-across-steps pre-activations
  k_mlp<<<dim3(4,32), 256, 0, stream>>>(U16(OFF_GENE), U16(OFF_WIHN), F32(OFF_BN),
      nullptr, F32(OFF_XWN), nullptr, 256, 2048, 0);
  k_mlp<<<dim3(4,32), 256, 0, stream>>>(U16(OFF_GENE), U16(OFF_WIHE1), F32(OFF_BE),
      nullptr, F32(OFF_XWEG), nullptr, 256, 2048, 0);

  // node phase: 62 sequential steps
  for (int s = 0; s < 62; ++s) {
    unsigned short* hin  = U16((s & 1) ? OFF_H1 : OFF_H0);
    unsigned short* hout = U16((s & 1) ? OFF_H0 : OFF_H1);
    k_lstm_node<<<dim3(4,8), 256, 0, stream>>>(hin, F32(OFF_C), F32(OFF_XWN),
        U16(OFF_WHHN), hout);
    k_mlp<<<dim3(4,4), 256, 0, stream>>>(hout, U16(OFF_WN1), bn1, nullptr,
        nullptr, U16(OFF_TN), 512, 256, 1);
    k_mlp<<<dim3(4,4), 256, 0, stream>>>(U16(OFF_TN), U16(OFF_WN2), bn2, nullptr,
        nullptr, U16(OFF_ENTRY), 256, 256, 0);
    k_mlp<<<dim3(4,32), 256, 0, stream>>>(U16(OFF_ENTRY), U16(OFF_WIHE2), nullptr,
        F32(OFF_XWEG), F32(OFF_XWEALL) + (size_t)s*256*2048, nullptr, 256, 2048, 0);
  }

  // edge phase: one persistent kernel, all chains
  k_edge<<<248, 512, 0, stream>>>(h0e, c0e, F32(OFF_XWEALL), U16(OFF_WHHE),
      U16(OFF_WE1), be1, U16(OFF_WE2), be2, U16(OFF_WE3), be3,
      U16(OFF_WSF), F32(OFF_BSF), U16(OFF_WS2), bs2, U16(OFF_WF2), bf2,
      (float*)d_out);
}